// Round 7
// baseline (516.633 us; speedup 1.0000x reference)
//
#include <hip/hip_runtime.h>

typedef __bf16 bf16x8 __attribute__((ext_vector_type(8)));
typedef float f32x4 __attribute__((ext_vector_type(4)));

#define INV_SQRT3f 0.57735026918962576f

// ---------------- kernel 0: weight prep into MFMA B-fragment layout ----------------
// For each weight W[c][w] (c = contraction, w = out col), place bf16 value at
// fragment slot: block (Wi,kt,ct) of 1KB, lane = (c&31)/8*16 + (w&15), j = c&7.
__global__ void wprep_kernel(const float* __restrict__ wss,
                             const float* __restrict__ wsv,
                             const float* __restrict__ wvs,
                             const float* __restrict__ wvv,
                             unsigned short* __restrict__ wfrag) {
  int tid = blockIdx.x * 256 + threadIdx.x;  // 0..65535
  int Wi = tid >> 14;
  int idx = tid & 16383;
  int c = idx >> 7;
  int w = idx & 127;
  const float* src = (Wi == 0) ? wss : (Wi == 1) ? wsv : (Wi == 2) ? wvs : wvv;
  float v = src[idx];
  if (Wi == 3) v *= INV_SQRT3f;  // fold inv_sqrt3 into w_vv
  unsigned u = __builtin_bit_cast(unsigned, v);
  u += 0x7FFFu + ((u >> 16) & 1u);  // RNE to bf16
  int kt = c >> 5, kk = c & 31, g = kk >> 3, j = kk & 7;
  int ct = w >> 4, n = w & 15;
  wfrag[(((Wi * 4 + kt) * 8 + ct) << 9) + (g * 16 + n) * 8 + j] = (unsigned short)(u >> 16);
}

// compile-time component select (indices constant after full unroll)
__device__ __forceinline__ float fc(const float4& v, int i) {
  return (i == 0) ? v.x : (i == 1) ? v.y : (i == 2) ? v.z : v.w;
}

// One kt-slice of a row's raw x data: 32 floats/lane (8 xs + 24 xv).
struct Chunk {
  float4 fs[2];
  float4 fv[6];
};

__device__ __forceinline__ void load_chunk(Chunk& c, const float* __restrict__ x,
                                           int rowA, int kt, int g) {
  const float* px = x + (size_t)rowA * 512;
#pragma unroll
  for (int q = 0; q < 2; ++q)
    c.fs[q] = *(const float4*)(px + kt * 32 + g * 8 + q * 4);
#pragma unroll
  for (int q = 0; q < 6; ++q)
    c.fv[q] = *(const float4*)(px + 128 + kt * 96 + g * 24 + q * 4);
}

// Fragments for one kt-slice. yv is folded into the A-side (sv_i = yv_i*xs),
// so the epilogue needs no y at all and accP is eliminated.
struct FragK {
  bf16x8 ss, sv0, sv1, sv2, dd, v0, v1, v2;
};

__device__ __forceinline__ void convert_chunk(FragK& F, const Chunk& c, const float4 yA) {
  const float ys = yA.x, yv0 = yA.y, yv1 = yA.z, yv2 = yA.w;
#pragma unroll
  for (int j = 0; j < 8; ++j) {
    float s = fc(c.fs[j >> 2], j & 3);
    float a = fc(c.fv[(3 * j) >> 2], (3 * j) & 3);
    float bb = fc(c.fv[(3 * j + 1) >> 2], (3 * j + 1) & 3);
    float cc = fc(c.fv[(3 * j + 2) >> 2], (3 * j + 2) & 3);
    F.ss[j] = (__bf16)(ys * s);
    F.sv0[j] = (__bf16)(yv0 * s);
    F.sv1[j] = (__bf16)(yv1 * s);
    F.sv2[j] = (__bf16)(yv2 * s);
    F.v0[j] = (__bf16)(ys * a);
    F.v1[j] = (__bf16)(ys * bb);
    F.v2[j] = (__bf16)(ys * cc);
    F.dd[j] = (__bf16)fmaf(a, yv0, fmaf(bb, yv1, cc * yv2));
  }
}

__device__ __forceinline__ void mfma_chunk(f32x4 (&accS)[8], f32x4 (&accV0)[8],
                                           f32x4 (&accV1)[8], f32x4 (&accV2)[8],
                                           const FragK& F, int kt,
                                           const unsigned short* wlds, int lofs) {
#pragma unroll
  for (int ct = 0; ct < 8; ++ct) {
    const bf16x8 Bss = *(const bf16x8*)&wlds[((0 * 4 + kt) * 8 + ct) * 512 + lofs];
    const bf16x8 Bsv = *(const bf16x8*)&wlds[((1 * 4 + kt) * 8 + ct) * 512 + lofs];
    const bf16x8 Bvs = *(const bf16x8*)&wlds[((2 * 4 + kt) * 8 + ct) * 512 + lofs];
    const bf16x8 Bvv = *(const bf16x8*)&wlds[((3 * 4 + kt) * 8 + ct) * 512 + lofs];
    accS[ct] = __builtin_amdgcn_mfma_f32_16x16x32_bf16(F.ss, Bss, accS[ct], 0, 0, 0);
    accS[ct] = __builtin_amdgcn_mfma_f32_16x16x32_bf16(F.dd, Bvv, accS[ct], 0, 0, 0);
    accV0[ct] = __builtin_amdgcn_mfma_f32_16x16x32_bf16(F.sv0, Bsv, accV0[ct], 0, 0, 0);
    accV0[ct] = __builtin_amdgcn_mfma_f32_16x16x32_bf16(F.v0, Bvs, accV0[ct], 0, 0, 0);
    accV1[ct] = __builtin_amdgcn_mfma_f32_16x16x32_bf16(F.sv1, Bsv, accV1[ct], 0, 0, 0);
    accV1[ct] = __builtin_amdgcn_mfma_f32_16x16x32_bf16(F.v1, Bvs, accV1[ct], 0, 0, 0);
    accV2[ct] = __builtin_amdgcn_mfma_f32_16x16x32_bf16(F.sv2, Bsv, accV2[ct], 0, 0, 0);
    accV2[ct] = __builtin_amdgcn_mfma_f32_16x16x32_bf16(F.v2, Bvs, accV2[ct], 0, 0, 0);
  }
}

// Structure, geometry, launch config IDENTICAL to the passing round-3 kernel
// (256 threads, launch_bounds(256,1), 128 KB LDS weight staging, B from LDS).
// ONE change: single chunk buffer with distance-1 prefetch instead of two
// buffers at distance-2 -> 32 fewer loop-carried registers, pushing the live
// set (~225 + temps) under the 256-VGPR line to eliminate the residual spill
// round-trips that serialize each t-iter.
__global__ __launch_bounds__(256, 1) void fused_kernel(
    const float* __restrict__ x, const float* __restrict__ y,
    const float* __restrict__ b, const unsigned short* __restrict__ wfrag,
    float* __restrict__ out) {
  __shared__ unsigned short wlds[65536];  // 128 KB: 4 weights x 4 kt x 8 ct x 1KB frag blocks
  {
    const float4* s = (const float4*)wfrag;
    float4* d = (float4*)wlds;
    const int t = threadIdx.x;
#pragma unroll
    for (int i = 0; i < 32; ++i) d[t + i * 256] = s[t + i * 256];
  }
  __syncthreads();

  const int wid = threadIdx.x >> 6;
  const int lane = threadIdx.x & 63;
  const int g = lane >> 4, li = lane & 15;
  const int lofs = lane * 8;  // ushort offset of this lane's 16B frag slice

  float breg[8];
#pragma unroll
  for (int ct = 0; ct < 8; ++ct) breg[ct] = b[ct * 16 + li];

  const int rowBase = blockIdx.x * 512 + wid * 16;
  const int rA0 = rowBase + li;

  // Distance-1 pipeline: ONE chunk in flight.
  Chunk C;
  load_chunk(C, x, rA0, 0, g);
  float4 yAc = *(const float4*)(y + (size_t)rA0 * 4);

  // t-loop NOT unrolled (unrolling duplicates live ranges -> spills).
#pragma unroll 1
  for (int t = 0; t < 8; ++t) {
    const int R0 = rowBase + t * 64;
    const int rowA = R0 + li;
    const int rowN = rowA + 64;

    f32x4 accS[8], accV0[8], accV1[8], accV2[8];
    const f32x4 zz = {0.f, 0.f, 0.f, 0.f};
#pragma unroll
    for (int ct = 0; ct < 8; ++ct) {
      accS[ct] = zz; accV0[ct] = zz; accV1[ct] = zz; accV2[ct] = zz;
    }

    float4 yAn;

    // ---- kt=0 ----
    {
      FragK F;
      convert_chunk(F, C, yAc);            // C raw regs die here
      load_chunk(C, x, rowA, 1, g);        // issue (t, kt=1)
      mfma_chunk(accS, accV0, accV1, accV2, F, 0, wlds, lofs);
    }
    // ---- kt=1 ----
    {
      FragK F;
      convert_chunk(F, C, yAc);
      load_chunk(C, x, rowA, 2, g);        // issue (t, kt=2)
      mfma_chunk(accS, accV0, accV1, accV2, F, 1, wlds, lofs);
    }
    // ---- kt=2 ----
    {
      FragK F;
      convert_chunk(F, C, yAc);
      load_chunk(C, x, rowA, 3, g);        // issue (t, kt=3)
      mfma_chunk(accS, accV0, accV1, accV2, F, 2, wlds, lofs);
    }
    // ---- kt=3 ----
    {
      FragK F;
      convert_chunk(F, C, yAc);
      if (t < 7) {
        load_chunk(C, x, rowN, 0, g);      // issue (t+1, kt=0)
        yAn = *(const float4*)(y + (size_t)rowN * 4);
      }
      mfma_chunk(accS, accV0, accV1, accV2, F, 3, wlds, lofs);
    }

    // epilogue: C/D layout col = lane&15, row = (lane>>4)*4 + reg [m89-verified].
    // No y needed (yv folded into A-frags). Stores are line-complete:
    // scalar = 4x64B contiguous runs/instr, float3 = 4x192B contiguous
    // 64B-aligned runs/instr.
#pragma unroll
    for (int rr = 0; rr < 4; ++rr) {
      const int row = R0 + g * 4 + rr;
      float* po = out + (size_t)row * 512;
#pragma unroll
      for (int ct = 0; ct < 8; ++ct) {
        po[ct * 16 + li] = accS[ct][rr] + breg[ct];
        const int w = ct * 16 + li;
        float3 o;
        o.x = accV0[ct][rr];
        o.y = accV1[ct][rr];
        o.z = accV2[ct][rr];
        *(float3*)(po + 128 + 3 * w) = o;  // 12B contiguous per lane -> dwordx3
      }
    }

    if (t < 7) yAc = yAn;
  }
}

extern "C" void kernel_launch(void* const* d_in, const int* in_sizes, int n_in,
                              void* d_out, int out_size, void* d_ws, size_t ws_size,
                              hipStream_t stream) {
  const float* x = (const float*)d_in[0];
  const float* y = (const float*)d_in[1];
  const float* wss = (const float*)d_in[2];
  const float* wsv = (const float*)d_in[3];
  const float* wvs = (const float*)d_in[4];
  const float* wvv = (const float*)d_in[5];
  const float* b = (const float*)d_in[6];
  float* out = (float*)d_out;
  unsigned short* wfrag = (unsigned short*)d_ws;  // 128 KB used

  wprep_kernel<<<256, 256, 0, stream>>>(wss, wsv, wvs, wvv, wfrag);
  fused_kernel<<<512, 256, 0, stream>>>(x, y, b, wfrag, out);
}

// Round 8
// 247.559 us; speedup vs baseline: 2.0869x; 2.0869x over previous
//
#include <hip/hip_runtime.h>

typedef __bf16 bf16x8 __attribute__((ext_vector_type(8)));
typedef float f32x4 __attribute__((ext_vector_type(4)));

#define INV_SQRT3f 0.57735026918962576f

// ---------------- kernel 0: weight prep into MFMA B-fragment layout ----------------
// For each weight W[c][w] (c = contraction, w = out col), place bf16 value at
// fragment slot: block (Wi,kt,ct) of 1KB, lane = (c&31)/8*16 + (w&15), j = c&7.
__global__ void wprep_kernel(const float* __restrict__ wss,
                             const float* __restrict__ wsv,
                             const float* __restrict__ wvs,
                             const float* __restrict__ wvv,
                             unsigned short* __restrict__ wfrag) {
  int tid = blockIdx.x * 256 + threadIdx.x;  // 0..65535
  int Wi = tid >> 14;
  int idx = tid & 16383;
  int c = idx >> 7;
  int w = idx & 127;
  const float* src = (Wi == 0) ? wss : (Wi == 1) ? wsv : (Wi == 2) ? wvs : wvv;
  float v = src[idx];
  if (Wi == 3) v *= INV_SQRT3f;  // fold inv_sqrt3 into w_vv
  unsigned u = __builtin_bit_cast(unsigned, v);
  u += 0x7FFFu + ((u >> 16) & 1u);  // RNE to bf16
  int kt = c >> 5, kk = c & 31, g = kk >> 3, j = kk & 7;
  int ct = w >> 4, n = w & 15;
  wfrag[(((Wi * 4 + kt) * 8 + ct) << 9) + (g * 16 + n) * 8 + j] = (unsigned short)(u >> 16);
}

// compile-time component select (indices constant after full unroll)
__device__ __forceinline__ float fc(const float4& v, int i) {
  return (i == 0) ? v.x : (i == 1) ? v.y : (i == 2) ? v.z : v.w;
}

// One kt-slice of a row's raw x data: 32 floats/lane (8 xs + 24 xv).
struct Chunk {
  float4 fs[2];
  float4 fv[6];
};

__device__ __forceinline__ void load_chunk(Chunk& c, const float* __restrict__ x,
                                           int rowA, int kt, int g) {
  const float* px = x + (size_t)rowA * 512;
#pragma unroll
  for (int q = 0; q < 2; ++q)
    c.fs[q] = *(const float4*)(px + kt * 32 + g * 8 + q * 4);
#pragma unroll
  for (int q = 0; q < 6; ++q)
    c.fv[q] = *(const float4*)(px + 128 + kt * 96 + g * 24 + q * 4);
}

// Fragments for one kt-slice. yv is folded into the A-side (sv_i = yv_i*xs),
// so the epilogue needs no y at all.
struct FragK {
  bf16x8 ss, sv0, sv1, sv2, dd, v0, v1, v2;
};

__device__ __forceinline__ void convert_chunk(FragK& F, const Chunk& c, const float4 yA) {
  const float ys = yA.x, yv0 = yA.y, yv1 = yA.z, yv2 = yA.w;
#pragma unroll
  for (int j = 0; j < 8; ++j) {
    float s = fc(c.fs[j >> 2], j & 3);
    float a = fc(c.fv[(3 * j) >> 2], (3 * j) & 3);
    float bb = fc(c.fv[(3 * j + 1) >> 2], (3 * j + 1) & 3);
    float cc = fc(c.fv[(3 * j + 2) >> 2], (3 * j + 2) & 3);
    F.ss[j] = (__bf16)(ys * s);
    F.sv0[j] = (__bf16)(yv0 * s);
    F.sv1[j] = (__bf16)(yv1 * s);
    F.sv2[j] = (__bf16)(yv2 * s);
    F.v0[j] = (__bf16)(ys * a);
    F.v1[j] = (__bf16)(ys * bb);
    F.v2[j] = (__bf16)(ys * cc);
    F.dd[j] = (__bf16)fmaf(a, yv0, fmaf(bb, yv1, cc * yv2));
  }
}

// Structure inverted vs round 7: A-fragments for all 4 kt stay RESIDENT
// (128 regs), the accumulator is STREAMED per-ct (16 regs live instead of
// 128).  Data live-set: FA 128 + one Chunk 32 + acc 16 + B-temps ~16-32
// -> ~60 regs of allocator headroom (rounds 0-7 had ~10 and spilled a
// loop-carried buffer to scratch: the 490 MB parasitic HBM traffic and the
// serialized ~200-900-cyc reload stalls that dominate at 1 wave/SIMD).
// Launch config / LDS staging / math / store pattern identical to the
// PASSING round-7 kernel.
__global__ __launch_bounds__(256, 1) void fused_kernel(
    const float* __restrict__ x, const float* __restrict__ y,
    const float* __restrict__ b, const unsigned short* __restrict__ wfrag,
    float* __restrict__ out) {
  __shared__ unsigned short wlds[65536];  // 128 KB: 4 weights x 4 kt x 8 ct x 1KB frag blocks
  {
    const float4* s = (const float4*)wfrag;
    float4* d = (float4*)wlds;
    const int t = threadIdx.x;
#pragma unroll
    for (int i = 0; i < 32; ++i) d[t + i * 256] = s[t + i * 256];
  }
  __syncthreads();

  const int wid = threadIdx.x >> 6;
  const int lane = threadIdx.x & 63;
  const int g = lane >> 4, li = lane & 15;
  const int lofs = lane * 8;  // ushort offset of this lane's 16B frag slice

  float breg[8];
#pragma unroll
  for (int ct = 0; ct < 8; ++ct) breg[ct] = b[ct * 16 + li];

  const int rowBase = blockIdx.x * 512 + wid * 16;
  const int rA0 = rowBase + li;

  // Distance-1 pipeline: ONE chunk buffer in flight.
  Chunk C;
  load_chunk(C, x, rA0, 0, g);
  float4 yAc = *(const float4*)(y + (size_t)rA0 * 4);

  // t-loop NOT unrolled (unrolling duplicates live ranges -> spills).
#pragma unroll 1
  for (int t = 0; t < 8; ++t) {
    const int R0 = rowBase + t * 64;
    const int rowA = R0 + li;
    const int rowN = rowA + 64;

    // ---- build phase: assemble ALL A-fragments for this iter ----
    FragK FA[4];  // fully-unrolled compile-time indexing only
    convert_chunk(FA[0], C, yAc);          // C(kt0) dies into FA[0]
    load_chunk(C, x, rowA, 1, g);
    convert_chunk(FA[1], C, yAc);
    load_chunk(C, x, rowA, 2, g);
    convert_chunk(FA[2], C, yAc);
    load_chunk(C, x, rowA, 3, g);
    convert_chunk(FA[3], C, yAc);
    float4 yAn;
    if (t < 7) {
      load_chunk(C, x, rowN, 0, g);        // (t+1, kt0): DEEP prefetch —
      yAn = *(const float4*)(y + (size_t)rowN * 4);  // whole MFMA phase ahead
    }

    // ---- MFMA + store phase: stream ct with a 16-reg accumulator ----
#pragma unroll
    for (int ct = 0; ct < 8; ++ct) {
      // bias folded into accS init (MFMA C-in accumulates)
      f32x4 aS = {breg[ct], breg[ct], breg[ct], breg[ct]};
      const f32x4 zz = {0.f, 0.f, 0.f, 0.f};
      f32x4 aV0 = zz, aV1 = zz, aV2 = zz;

#pragma unroll
      for (int kt = 0; kt < 4; ++kt) {
        const bf16x8 Bss = *(const bf16x8*)&wlds[((0 * 4 + kt) * 8 + ct) * 512 + lofs];
        const bf16x8 Bsv = *(const bf16x8*)&wlds[((1 * 4 + kt) * 8 + ct) * 512 + lofs];
        const bf16x8 Bvs = *(const bf16x8*)&wlds[((2 * 4 + kt) * 8 + ct) * 512 + lofs];
        const bf16x8 Bvv = *(const bf16x8*)&wlds[((3 * 4 + kt) * 8 + ct) * 512 + lofs];
        aS  = __builtin_amdgcn_mfma_f32_16x16x32_bf16(FA[kt].ss,  Bss, aS,  0, 0, 0);
        aS  = __builtin_amdgcn_mfma_f32_16x16x32_bf16(FA[kt].dd,  Bvv, aS,  0, 0, 0);
        aV0 = __builtin_amdgcn_mfma_f32_16x16x32_bf16(FA[kt].sv0, Bsv, aV0, 0, 0, 0);
        aV0 = __builtin_amdgcn_mfma_f32_16x16x32_bf16(FA[kt].v0,  Bvs, aV0, 0, 0, 0);
        aV1 = __builtin_amdgcn_mfma_f32_16x16x32_bf16(FA[kt].sv1, Bsv, aV1, 0, 0, 0);
        aV1 = __builtin_amdgcn_mfma_f32_16x16x32_bf16(FA[kt].v1,  Bvs, aV1, 0, 0, 0);
        aV2 = __builtin_amdgcn_mfma_f32_16x16x32_bf16(FA[kt].sv2, Bsv, aV2, 0, 0, 0);
        aV2 = __builtin_amdgcn_mfma_f32_16x16x32_bf16(FA[kt].v2,  Bvs, aV2, 0, 0, 0);
      }

      // per-ct epilogue: C/D layout col = lane&15, row = (lane>>4)*4 + reg
      // [m89-verified].  Stores line-complete: scalar halves merge across
      // adjacent ct phases; float3 = 192B contiguous 64B-aligned runs whose
      // companion half-lines land in the adjacent ct phase (~400 cyc apart,
      // well inside L2 dirty-line residency).
#pragma unroll
      for (int rr = 0; rr < 4; ++rr) {
        const int row = R0 + g * 4 + rr;
        float* po = out + (size_t)row * 512;
        po[ct * 16 + li] = aS[rr];
        const int w = ct * 16 + li;
        float3 o;
        o.x = aV0[rr];
        o.y = aV1[rr];
        o.z = aV2[rr];
        *(float3*)(po + 128 + 3 * w) = o;  // 12B contiguous per lane -> dwordx3
      }
    }

    if (t < 7) yAc = yAn;
  }
}

extern "C" void kernel_launch(void* const* d_in, const int* in_sizes, int n_in,
                              void* d_out, int out_size, void* d_ws, size_t ws_size,
                              hipStream_t stream) {
  const float* x = (const float*)d_in[0];
  const float* y = (const float*)d_in[1];
  const float* wss = (const float*)d_in[2];
  const float* wsv = (const float*)d_in[3];
  const float* wvs = (const float*)d_in[4];
  const float* wvv = (const float*)d_in[5];
  const float* b = (const float*)d_in[6];
  float* out = (float*)d_out;
  unsigned short* wfrag = (unsigned short*)d_ws;  // 128 KB used

  wprep_kernel<<<256, 256, 0, stream>>>(wss, wsv, wvs, wvv, wfrag);
  fused_kernel<<<512, 256, 0, stream>>>(x, y, b, wfrag, out);
}